// Round 1
// baseline (267.935 us; speedup 1.0000x reference)
//
#include <hip/hip_runtime.h>
#include <stdint.h>

#define DEV __device__ __forceinline__

typedef unsigned short u16;
typedef __bf16 bf16x8 __attribute__((ext_vector_type(8)));
typedef float f32x4 __attribute__((ext_vector_type(4)));
typedef u16 u16x8 __attribute__((ext_vector_type(8)));

#define MFMA_BF16(A, B, C) __builtin_amdgcn_mfma_f32_16x16x32_bf16(A, B, C, 0, 0, 0)
#define EXP2(x) __builtin_amdgcn_exp2f(x)

DEV u16 f2bf(float f) {
    unsigned x;
    __builtin_memcpy(&x, &f, 4);
    unsigned r = (x + 0x7fffu + ((x >> 16) & 1u)) >> 16;  // RNE
    return (u16)r;
}

DEV u16 f2bf_fast(float f) {  // round-half-up; 2 VALU ops, used in attn hot loop
    unsigned x;
    __builtin_memcpy(&x, &f, 4);
    return (u16)((x + 0x8000u) >> 16);
}

DEV void storeC(u16* p, float v) { *p = f2bf(v); }
DEV void storeC(float* p, float v) { *p = v; }

// async global->LDS, 16B per lane. LDS dest must be wave-uniform base + lane*16.
DEV void async_copy16(const u16* g, u16* l) {
    __builtin_amdgcn_global_load_lds(
        (__attribute__((address_space(1))) unsigned int*)g,
        (__attribute__((address_space(3))) unsigned int*)l, 16, 0, 0);
}

// barrier with compiler memory fence on both sides (builtin s_barrier alone is
// not modeled as a memory fence; the empty asm pins LDS ops to this side).
DEV void wg_barrier() {
    asm volatile("" ::: "memory");
    __builtin_amdgcn_s_barrier();
    asm volatile("" ::: "memory");
}

// ---------------------------------------------------------------------------
// fused fp32 -> bf16 conversion of x | wqkv | wout into one contiguous dest.
// ---------------------------------------------------------------------------
constexpr int N_X = 8192 * 1024, N_WQ = 3072 * 1024, N_WO = 1024 * 1024;

__global__ __launch_bounds__(256)
void cvt_all(const float* __restrict__ x, const float* __restrict__ wq,
             const float* __restrict__ wo, u16* __restrict__ out) {
    const int i = (blockIdx.x * 256 + threadIdx.x) * 4;
    const float* src;
    if (i < N_X) src = x + i;
    else if (i < N_X + N_WQ) src = wq + (i - N_X);
    else src = wo + (i - N_X - N_WQ);
    const float4 v = *(const float4*)src;
    ushort4 o;
    o.x = f2bf(v.x);
    o.y = f2bf(v.y);
    o.z = f2bf(v.z);
    o.w = f2bf(v.w);
    *(ushort4*)(out + i) = o;
}

// ---------------------------------------------------------------------------
// 8-phase-style pipelined GEMM: C[M,N] = A[M,K] * Bw[N,K]^T + bias[N].
// Tile 256x128, BK=64, 512 threads = 8 waves (4M x 2N), per-wave 64x64 out.
// Triple-buffered LDS (A: 3x32KB, B: 3x16KB = 144KB) -> stage tile t+2 into
// the slot tile t-1 vacated: no overwrite race by construction. Counted
// vmcnt(6) once per K-tile (never 0 mid-loop); raw s_barrier (no drain);
// setprio(1) around each 16-MFMA cluster; 2 phases per K-tile.
// LDS swizzle: phys_byte = row*128 + (colb ^ ((row&7)<<4))  (involution).
// global_load_lds writes linearly, so the GLOBAL source is inverse-swizzled:
//   row = p*64 + tid>>3, col = ((tid&7) ^ ((tid>>3)&7))*8   (rule #21).
// VSPLIT: cols >= 2048 (V third of QKV) stored transposed into vT[col'][row].
// ---------------------------------------------------------------------------
template <typename OT, bool VSPLIT>
__global__ __launch_bounds__(512, 2)
void gemm_8ph(const u16* __restrict__ A, const u16* __restrict__ Bw,
              const float* __restrict__ bias, OT* __restrict__ C,
              u16* __restrict__ vT, int M, int N, int K, int ntn) {
    __shared__ __attribute__((aligned(16))) u16 sA[3][256 * 64];
    __shared__ __attribute__((aligned(16))) u16 sB[3][128 * 64];

    const int tid  = threadIdx.x;
    const int lane = tid & 63;
    const int wave = tid >> 6;
    const int fr = lane & 15;
    const int q4 = lane >> 4;
    const int wr = wave >> 1;  // 0..3: M quarter
    const int wc = wave & 1;   // 0..1: N half

    // XCD-aware bijective swizzle (grid % 8 == 0), n-fastest so each XCD's
    // chunk reuses a ~2MB A row-panel from its L2 while B streams from L3.
    const int cpx = gridDim.x >> 3;
    const int wg = (blockIdx.x & 7) * cpx + (blockIdx.x >> 3);
    const int mt = wg / ntn, nt = wg % ntn;
    const int m0 = mt * 256, n0 = nt * 128;

    // staging source mapping (inverse swizzle, constant per thread)
    const int crow = tid >> 3;
    const int ccol = ((tid & 7) ^ (crow & 7)) * 8;
    const u16* pA = A + (size_t)(m0 + crow) * K + ccol;
    const u16* pB = Bw + (size_t)(n0 + crow) * K + ccol;
    const size_t rK = (size_t)64 * K;  // 64 rows of stride K

    const int NT = K >> 6;

    f32x4 acc[4][4];
#pragma unroll
    for (int i = 0; i < 4; i++)
#pragma unroll
        for (int j = 0; j < 4; j++) acc[i][j] = (f32x4){0.f, 0.f, 0.f, 0.f};

    // prologue: stage tiles 0 and 1 (6 loads each, in order)
#pragma unroll
    for (int p = 0; p < 4; p++) async_copy16(pA + p * rK, &sA[0][p * 4096 + tid * 8]);
#pragma unroll
    for (int p = 0; p < 2; p++) async_copy16(pB + p * rK, &sB[0][p * 4096 + tid * 8]);
#pragma unroll
    for (int p = 0; p < 4; p++) async_copy16(pA + p * rK + 64, &sA[1][p * 4096 + tid * 8]);
#pragma unroll
    for (int p = 0; p < 2; p++) async_copy16(pB + p * rK + 64, &sB[1][p * 4096 + tid * 8]);
    asm volatile("s_waitcnt vmcnt(6)" ::: "memory");  // tile 0 landed, tile 1 in flight
    wg_barrier();

    int sl = 0;  // ring slot of current tile
    for (int t = 0; t < NT; ++t) {
        const u16* bufA = sA[sl];
        const u16* bufB = sB[sl];
        const int s2 = (sl >= 1) ? sl - 1 : 2;  // (sl+2)%3 : slot tile t-1 vacated
        const bool st = (t + 2 < NT);
        const int ko = (t + 2) * 64;

        bf16x8 af[4][2], bf[4][2];

        // ---------------- phase 1: read A(all) + B(j0,j1); stage 3; mfma j0,j1
#pragma unroll
        for (int i = 0; i < 4; i++) {
            const int row = wr * 64 + i * 16 + fr;
#pragma unroll
            for (int kk = 0; kk < 2; kk++)
                af[i][kk] = *(const bf16x8*)
                    &bufA[row * 64 + (((kk * 64 + q4 * 16) ^ ((row & 7) << 4)) >> 1)];
        }
#pragma unroll
        for (int j = 0; j < 2; j++) {
            const int row = wc * 64 + j * 16 + fr;
#pragma unroll
            for (int kk = 0; kk < 2; kk++)
                bf[j][kk] = *(const bf16x8*)
                    &bufB[row * 64 + (((kk * 64 + q4 * 16) ^ ((row & 7) << 4)) >> 1)];
        }
        if (st) {
#pragma unroll
            for (int p = 0; p < 3; p++)
                async_copy16(pA + p * rK + ko, &sA[s2][p * 4096 + tid * 8]);
        }
        wg_barrier();
        __builtin_amdgcn_s_setprio(1);
#pragma unroll
        for (int i = 0; i < 4; i++)
#pragma unroll
            for (int j = 0; j < 2; j++) {
                acc[i][j] = MFMA_BF16(af[i][0], bf[j][0], acc[i][j]);
                acc[i][j] = MFMA_BF16(af[i][1], bf[j][1], acc[i][j]);
            }
        __builtin_amdgcn_s_setprio(0);
        wg_barrier();

        // ---------------- phase 2: read B(j2,j3); stage 3; checkpoint; mfma j2,j3
#pragma unroll
        for (int j = 2; j < 4; j++) {
            const int row = wc * 64 + j * 16 + fr;
#pragma unroll
            for (int kk = 0; kk < 2; kk++)
                bf[j][kk] = *(const bf16x8*)
                    &bufB[row * 64 + (((kk * 64 + q4 * 16) ^ ((row & 7) << 4)) >> 1)];
        }
        if (st) {
            async_copy16(pA + 3 * rK + ko, &sA[s2][3 * 4096 + tid * 8]);
#pragma unroll
            for (int p = 0; p < 2; p++)
                async_copy16(pB + p * rK + ko, &sB[s2][p * 4096 + tid * 8]);
        }
        // once-per-tile checkpoint: tile t+1 must have landed; tile t+2's 6
        // loads may stay in flight. Drain only at the pipeline tail.
        if (t < NT - 2) asm volatile("s_waitcnt vmcnt(6)" ::: "memory");
        else            asm volatile("s_waitcnt vmcnt(0)" ::: "memory");
        wg_barrier();
        __builtin_amdgcn_s_setprio(1);
#pragma unroll
        for (int i = 0; i < 4; i++)
#pragma unroll
            for (int j = 2; j < 4; j++) {
                acc[i][j] = MFMA_BF16(af[i][0], bf[j][0], acc[i][j]);
                acc[i][j] = MFMA_BF16(af[i][1], bf[j][1], acc[i][j]);
            }
        __builtin_amdgcn_s_setprio(0);
        wg_barrier();

        sl = (sl < 2) ? sl + 1 : 0;
    }

    // epilogue: C/D layout col=lane&15, row=quad*4+reg  [verified m89/m91]
#pragma unroll
    for (int j = 0; j < 4; j++) {
        const int col = n0 + wc * 64 + j * 16 + fr;
        const float bv = bias[col];
        if (VSPLIT && col >= 2048) {  // wave-uniform per j (col base 16-aligned)
#pragma unroll
            for (int i = 0; i < 4; i++) {
                const int row = m0 + wr * 64 + i * 16 + q4 * 4;
                ushort4 o;
                o.x = f2bf(acc[i][j][0] + bv);
                o.y = f2bf(acc[i][j][1] + bv);
                o.z = f2bf(acc[i][j][2] + bv);
                o.w = f2bf(acc[i][j][3] + bv);
                *(ushort4*)&vT[(size_t)(col - 2048) * 8192 + row] = o;
            }
        } else {
#pragma unroll
            for (int i = 0; i < 4; i++) {
                const int row = m0 + wr * 64 + i * 16 + q4 * 4;
#pragma unroll
                for (int r = 0; r < 4; r++)
                    storeC(&C[(size_t)(row + r) * N + col], acc[i][j][r] + bv);
            }
        }
    }
}

// ---------------------------------------------------------------------------
// Flash attention, causal, S^T/O^T formulation, PAIRED Q-TILES, XCD-GROUPED.
// (unchanged this round — see session notes; next target after GEMM.)
// ---------------------------------------------------------------------------
constexpr int Lc = 2048, Dc = 1024;

__global__ __launch_bounds__(256, 4)
void attn_fa(const u16* __restrict__ qkv, const u16* __restrict__ vT,
             u16* __restrict__ outb) {
    __shared__ __attribute__((aligned(16))) u16 sK[64 * 72];        // [key][d]
    __shared__ __attribute__((aligned(16))) u16 sVT[64 * 72];       // [d][key]
    __shared__ __attribute__((aligned(16))) u16 sP[4][2][16 * 72];  // [wave][tile][q][key]

    const int tid  = threadIdx.x;
    const int lane = tid & 63;
    const int wave = tid >> 6;
    const int fr = lane & 15;
    const int q4 = lane >> 4;

    const int id = blockIdx.x;                  // 0..1023
    const int g  = (id & 7) + 8 * (id >> 7);    // (b,h) group, XCD = g & 7
    const int bx = (id >> 3) & 15;              // 0..15
    const int h = g & 15;
    const int b = g >> 4;
    const int qblkA = bx;                       // short tile
    const int qblkB = 31 - bx;                  // long tile

    constexpr float CEXP = 0.18033688011112042f;  // 0.125 * log2(e)

    const int qrowA = qblkA * 64 + wave * 16 + fr;
    const int qrowB = qblkB * 64 + wave * 16 + fr;
    const u16* qptrA = qkv + ((size_t)(b * Lc + qrowA) * 3) * Dc + h * 64;
    const u16* qptrB = qkv + ((size_t)(b * Lc + qrowB) * 3) * Dc + h * 64;
    bf16x8 qfA[2], qfB[2];
    qfA[0] = *(const bf16x8*)(qptrA + q4 * 8);
    qfA[1] = *(const bf16x8*)(qptrA + 32 + q4 * 8);
    qfB[0] = *(const bf16x8*)(qptrB + q4 * 8);
    qfB[1] = *(const bf16x8*)(qptrB + 32 + q4 * 8);

    f32x4 oA[4], oB[4];
#pragma unroll
    for (int t = 0; t < 4; t++) {
        oA[t] = (f32x4){0.f, 0.f, 0.f, 0.f};
        oB[t] = (f32x4){0.f, 0.f, 0.f, 0.f};
    }
    float mA = -3.4e38f, lA = 0.f, mB = -3.4e38f, lB = 0.f;

    const int q_local = wave * 16 + fr;

    const int rr = tid >> 3;
    const int oo = tid & 7;
    const u16* kg = qkv + ((size_t)(b * Lc) * 3 + 1) * Dc + h * 64 + oo * 8;  // + tok*3072
    const u16* vg = vT + (size_t)(h * 64) * 8192 + b * Lc + oo * 8;           // + d*8192 + key

    u16x8 kr[2], vr[2];
#pragma unroll
    for (int c = 0; c < 2; ++c) {
        kr[c] = *(const u16x8*)(kg + (size_t)(c * 32 + rr) * 3072);
        vr[c] = *(const u16x8*)(vg + (size_t)(c * 32 + rr) * 8192);
    }

    u16* sPA = &sP[wave][0][0];
    u16* sPB = &sP[wave][1][0];

    for (int jb = 0; jb <= qblkB; ++jb) {
        __syncthreads();
#pragma unroll
        for (int c = 0; c < 2; ++c) {
            *(u16x8*)&sK[(c * 32 + rr) * 72 + oo * 8] = kr[c];
            *(u16x8*)&sVT[(c * 32 + rr) * 72 + oo * 8] = vr[c];
        }
        __syncthreads();
        if (jb < qblkB) {
#pragma unroll
            for (int c = 0; c < 2; ++c) {
                kr[c] = *(const u16x8*)(kg + (size_t)((jb + 1) * 64 + c * 32 + rr) * 3072);
                vr[c] = *(const u16x8*)(vg + (size_t)(c * 32 + rr) * 8192 + (jb + 1) * 64);
            }
        }

        const bool doA = (jb <= qblkA);  // wave-uniform

        f32x4 sA_[4], sB_[4];
#pragma unroll
        for (int t = 0; t < 4; t++) {
            const bf16x8 kf0 = *(const bf16x8*)&sK[(t * 16 + fr) * 72 + q4 * 8];
            const bf16x8 kf1 = *(const bf16x8*)&sK[(t * 16 + fr) * 72 + 32 + q4 * 8];
            sB_[t] = (f32x4){0.f, 0.f, 0.f, 0.f};
            sB_[t] = MFMA_BF16(kf0, qfB[0], sB_[t]);
            sB_[t] = MFMA_BF16(kf1, qfB[1], sB_[t]);
            if (doA) {
                sA_[t] = (f32x4){0.f, 0.f, 0.f, 0.f};
                sA_[t] = MFMA_BF16(kf0, qfA[0], sA_[t]);
                sA_[t] = MFMA_BF16(kf1, qfA[1], sA_[t]);
            }
        }

        // ---- tile B softmax ----
        {
            if (jb == qblkB) {
#pragma unroll
                for (int t = 0; t < 4; t++)
#pragma unroll
                    for (int r = 0; r < 4; r++)
                        if (t * 16 + q4 * 4 + r > q_local) sB_[t][r] = -1e30f;
            }
            float mx = sB_[0][0];
#pragma unroll
            for (int t = 0; t < 4; t++)
#pragma unroll
                for (int r = 0; r < 4; r++) mx = fmaxf(mx, sB_[t][r]);
            mx = fmaxf(mx, __shfl_xor(mx, 16));
            mx = fmaxf(mx, __shfl_xor(mx, 32));
            const float mnew = fmaxf(mB, mx);
            const float alpha = EXP2((mB - mnew) * CEXP);
            float sum = 0.f;
#pragma unroll
            for (int t = 0; t < 4; t++) {
#pragma unroll
                for (int r = 0; r < 4; r++) {
                    const float p = EXP2((sB_[t][r] - mnew) * CEXP);
                    sB_[t][r] = p;
                    sum += p;
                }
                ushort4 o;
                o.x = f2bf_fast(sB_[t][0]);
                o.y = f2bf_fast(sB_[t][1]);
                o.z = f2bf_fast(sB_[t][2]);
                o.w = f2bf_fast(sB_[t][3]);
                *(ushort4*)&sPB[fr * 72 + t * 16 + q4 * 4] = o;
            }
            sum += __shfl_xor(sum, 16);
            sum += __shfl_xor(sum, 32);
            lB = alpha * lB + sum;
            mB = mnew;
#pragma unroll
            for (int t = 0; t < 4; t++)
#pragma unroll
                for (int r = 0; r < 4; r++) oB[t][r] *= alpha;
        }

        // ---- tile A softmax ----
        if (doA) {
            if (jb == qblkA) {
#pragma unroll
                for (int t = 0; t < 4; t++)
#pragma unroll
                    for (int r = 0; r < 4; r++)
                        if (t * 16 + q4 * 4 + r > q_local) sA_[t][r] = -1e30f;
            }
            float mx = sA_[0][0];
#pragma unroll
            for (int t = 0; t < 4; t++)
#pragma unroll
                for (int r = 0; r < 4; r++) mx = fmaxf(mx, sA_[t][r]);
            mx = fmaxf(mx, __shfl_xor(mx, 16));
            mx = fmaxf(mx, __shfl_xor(mx, 32));
            const float mnew = fmaxf(mA, mx);
            const float alpha = EXP2((mA - mnew) * CEXP);
            float sum = 0.f;
#pragma unroll
            for (int t = 0; t < 4; t++) {
#pragma unroll
                for (int r = 0; r < 4; r++) {
                    const float p = EXP2((sA_[t][r] - mnew) * CEXP);
                    sA_[t][r] = p;
                    sum += p;
                }
                ushort4 o;
                o.x = f2bf_fast(sA_[t][0]);
                o.y = f2bf_fast(sA_[t][1]);
                o.z = f2bf_fast(sA_[t][2]);
                o.w = f2bf_fast(sA_[t][3]);
                *(ushort4*)&sPA[fr * 72 + t * 16 + q4 * 4] = o;
            }
            sum += __shfl_xor(sum, 16);
            sum += __shfl_xor(sum, 32);
            lA = alpha * lA + sum;
            mA = mnew;
#pragma unroll
            for (int t = 0; t < 4; t++)
#pragma unroll
                for (int r = 0; r < 4; r++) oA[t][r] *= alpha;
        }

        // O^T += V^T P^T
#pragma unroll
        for (int ks = 0; ks < 2; ++ks) {
            const bf16x8 pfB = *(const bf16x8*)&sPB[fr * 72 + ks * 32 + q4 * 8];
            bf16x8 pfA;
            if (doA) pfA = *(const bf16x8*)&sPA[fr * 72 + ks * 32 + q4 * 8];
#pragma unroll
            for (int t = 0; t < 4; t++) {
                const bf16x8 vf = *(const bf16x8*)&sVT[(t * 16 + fr) * 72 + ks * 32 + q4 * 8];
                oB[t] = MFMA_BF16(vf, pfB, oB[t]);
                if (doA) oA[t] = MFMA_BF16(vf, pfA, oA[t]);
            }
        }
    }

    const float rlA = 1.0f / lA;
    const float rlB = 1.0f / lB;
    u16* orowA = outb + (size_t)(b * Lc + qblkA * 64 + wave * 16 + fr) * Dc + h * 64;
    u16* orowB = outb + (size_t)(b * Lc + qblkB * 64 + wave * 16 + fr) * Dc + h * 64;
#pragma unroll
    for (int t = 0; t < 4; t++) {
        ushort4 a, o;
        a.x = f2bf(oA[t][0] * rlA);
        a.y = f2bf(oA[t][1] * rlA);
        a.z = f2bf(oA[t][2] * rlA);
        a.w = f2bf(oA[t][3] * rlA);
        *(ushort4*)(orowA + t * 16 + q4 * 4) = a;
        o.x = f2bf(oB[t][0] * rlB);
        o.y = f2bf(oB[t][1] * rlB);
        o.z = f2bf(oB[t][2] * rlB);
        o.w = f2bf(oB[t][3] * rlB);
        *(ushort4*)(orowB + t * 16 + q4 * 4) = o;
    }
}

// ---------------------------------------------------------------------------
extern "C" void kernel_launch(void* const* d_in, const int* in_sizes, int n_in,
                              void* d_out, int out_size, void* d_ws, size_t ws_size,
                              hipStream_t stream) {
    const float* x    = (const float*)d_in[0];  // [4,2048,1024] fp32
    const float* wqkv = (const float*)d_in[1];  // [3072,1024]
    const float* bqkv = (const float*)d_in[2];  // [3072]
    const float* wout = (const float*)d_in[3];  // [1024,1024]
    const float* bout = (const float*)d_in[4];  // [1024]
    float* out = (float*)d_out;                 // [4,2048,1024] fp32

    u16* qkv    = (u16*)d_ws;                       // [8192,3072] bf16 (V third unused)
    u16* attn   = qkv + (size_t)8192 * 3072;        // [8192,1024] bf16
    u16* xbf    = attn + (size_t)8192 * 1024;       // [8192,1024] bf16
    u16* wqkvbf = xbf + (size_t)8192 * 1024;        // [3072,1024] bf16
    u16* woutbf = wqkvbf + (size_t)3072 * 1024;     // [1024,1024] bf16
    u16* vT     = woutbf + (size_t)1024 * 1024;     // [1024, 8192] bf16 (V transposed)

    cvt_all<<<(N_X + N_WQ + N_WO) / 1024, dim3(256), 0, stream>>>(x, wqkv, wout, xbf);

    // QKV: 256x128 tiles -> grid 32*24 = 768 = 3 full CU rounds
    gemm_8ph<u16, true><<<dim3(768), dim3(512), 0, stream>>>(
        xbf, wqkvbf, bqkv, qkv, vT, 8192, 3072, 1024, 24);
    attn_fa<<<dim3(1024), dim3(256), 0, stream>>>(qkv, vT, attn);
    // out-proj: 32*8 = 256 = exactly 1 block per CU
    gemm_8ph<float, false><<<dim3(256), dim3(512), 0, stream>>>(
        attn, woutbf, bout, out, nullptr, 8192, 1024, 1024, 8);
}